// Round 2
// baseline (359.989 us; speedup 1.0000x reference)
//
#include <hip/hip_runtime.h>
#include <math.h>

#define QTOT 65536
#define CC 64
#define DD 512
#define QB 64            /* queries per block */
#define BLK 256
#define EXS 68           /* dots/e-value row stride in floats (272 B) */

typedef _Float16 half8 __attribute__((ext_vector_type(8)));
typedef float floatx4 __attribute__((ext_vector_type(4)));

/* ws float layout:
   [0] sum c_f  [1] sum c_r  [2] n_r  [3] masked g_f  [4] masked g_r
   [16..144) proto norms (rgb 64 then flow 64)
   [256..256+65536) g_f   [256+65536..) g_r
   [256+2*65536 ..) f16 protos, window-relabeled frag order (see k0), 32768 halfs/mod */
enum { WS_SCF = 0, WS_SCR = 1, WS_CNT = 2, WS_MGF = 3, WS_MGR = 4,
       WS_NP = 16, WS_GF = 256, WS_GR = 256 + QTOT, WS_PH = 256 + 2 * QTOT };

/* K0: proto norms (fp32) + f16 conversion into the window-relabeled frag order.
   k-group g (orig k = 8g..8g+7) -> chunk c = (g>>4)*4 + (g&3), kk = ((g>>2)&3)*8.
   This pairs with k1's A-side where lane-quad owns a CONTIGUOUS 128-B region
   (orig-k [quad*32, quad*32+32)) of each 512-B window. */
__global__ __launch_bounds__(64) void k0_prep(
    const float* __restrict__ ctx_r, const float* __restrict__ ctx_f,
    float* ws) {
  const int b = blockIdx.x;        /* 0..127 = mod*64 + proto */
  const int lane = threadIdx.x;
  const int m = b >> 6, p = b & 63;
  const float* row = ((m == 0) ? ctx_r : ctx_f) + (size_t)p * DD;
  const float4* r4 = (const float4*)row;
  float s = 0.f;
#pragma unroll
  for (int i = 0; i < 2; ++i) {
    float4 v = r4[lane + i * 64];
    s = fmaf(v.x, v.x, s); s = fmaf(v.y, v.y, s);
    s = fmaf(v.z, v.z, s); s = fmaf(v.w, v.w, s);
  }
#pragma unroll
  for (int off = 32; off > 0; off >>= 1) s += __shfl_xor(s, off);
  if (lane == 0) ws[WS_NP + b] = s;
  if (b == 0 && lane < 16) ws[lane] = 0.f;

  /* f16 conversion: lane = k-group g; dest chunk/kk per window relabeling */
  _Float16* hF = (_Float16*)(ws + WS_PH);
  float4 a = r4[lane * 2], c = r4[lane * 2 + 1];
  half8 h;
  h[0] = (_Float16)a.x; h[1] = (_Float16)a.y; h[2] = (_Float16)a.z; h[3] = (_Float16)a.w;
  h[4] = (_Float16)c.x; h[5] = (_Float16)c.y; h[6] = (_Float16)c.z; h[7] = (_Float16)c.w;
  const int chunk = (lane >> 4) * 4 + (lane & 3);
  const int kk = ((lane >> 2) & 3) * 8;
  *(half8*)&hF[m * 32768 + chunk * 2048 + p * 32 + kk] = h;
}

/* K1: wave w = mw*2+qh (modality, query-half). MFMA 16x16x32 f16.
   A is read in 512-B-per-row WINDOWS: lane(quad,col) owns the contiguous
   128-B region [quad*128, quad*128+128) of rows (qh*32+col) and (+16) within
   each window -> DRAM sees 4-consecutive-line bursts instead of the previous
   stride-2KB 128-B scatter (which capped HBM at ~1.2 TB/s).
   Per sub-chunk s: cvt 2 freed float4-pairs, prefetch B(c+1), issue 4 A-loads
   of the NEXT window into the just-freed registers (distance = 4 subs), 8 MFMA.
   No LDS / no barriers in the loop. Epilogue (verified) byte-identical. */
__global__ __launch_bounds__(BLK, 3) void k1_main(
    const float* __restrict__ tgt_r, const float* __restrict__ tgt_f,
    float* ws, float* __restrict__ out) {
  __shared__ __align__(16) float arena[2 * QB * EXS];  /* 34816 B */
  __shared__ float xmin[4][QB];
  __shared__ float xS[4][QB];
  __shared__ float xT[4][QB];
  __shared__ float xM[4][QB];
  __shared__ float xI[2][QB];
  __shared__ float nqA[2][QB];

  const int tid = threadIdx.x;
  const int w = tid >> 6, lane = tid & 63;
  const int mw = w >> 1, qh = w & 1;
  const int col = lane & 15, quad = lane >> 4;
  const int q0 = blockIdx.x * QB;

  const _Float16* hF = (const _Float16*)(ws + WS_PH);
  const float* tgt = mw ? tgt_f : tgt_r;
  /* lane's region base: row (qh*32 [+16] + col), byte offset quad*128 */
  const float4* a0 = (const float4*)(tgt + (size_t)(q0 + qh * 32 + col) * DD) + quad * 8;
  const float4* a1 = (const float4*)(tgt + (size_t)(q0 + qh * 32 + 16 + col) * DD) + quad * 8;
  const _Float16* bb = hF + mw * 32768 + col * 32 + quad * 8;

  floatx4 acc[2][4];
#pragma unroll
  for (int t = 0; t < 2; ++t)
#pragma unroll
    for (int u = 0; u < 4; ++u) acc[t][u] = (floatx4){0.f, 0.f, 0.f, 0.f};

  /* F[j] = t0-row granule j; F[8+j] = t1-row granule j (window-local j=0..7) */
  float4 F[16];
  half8 Bb[2][4];
#pragma unroll
  for (int j = 0; j < 8; ++j) { F[j] = a0[j]; F[8 + j] = a1[j]; }
#pragma unroll
  for (int u = 0; u < 4; ++u) Bb[0][u] = *(const half8*)&bb[u * 512];

  float n0 = 0.f, n1 = 0.f;
#pragma unroll
  for (int w4 = 0; w4 < 4; ++w4) {
#pragma unroll
    for (int s = 0; s < 4; ++s) {
      const int c = w4 * 4 + s;
      float4 x0 = F[2 * s], x1 = F[2 * s + 1];
      float4 y0 = F[8 + 2 * s], y1 = F[9 + 2 * s];
      half8 h0, h1;
      h0[0] = (_Float16)x0.x; h0[1] = (_Float16)x0.y; h0[2] = (_Float16)x0.z; h0[3] = (_Float16)x0.w;
      h0[4] = (_Float16)x1.x; h0[5] = (_Float16)x1.y; h0[6] = (_Float16)x1.z; h0[7] = (_Float16)x1.w;
      h1[0] = (_Float16)y0.x; h1[1] = (_Float16)y0.y; h1[2] = (_Float16)y0.z; h1[3] = (_Float16)y0.w;
      h1[4] = (_Float16)y1.x; h1[5] = (_Float16)y1.y; h1[6] = (_Float16)y1.z; h1[7] = (_Float16)y1.w;
      n0 = fmaf(x0.x, x0.x, n0); n0 = fmaf(x0.y, x0.y, n0);
      n0 = fmaf(x0.z, x0.z, n0); n0 = fmaf(x0.w, x0.w, n0);
      n0 = fmaf(x1.x, x1.x, n0); n0 = fmaf(x1.y, x1.y, n0);
      n0 = fmaf(x1.z, x1.z, n0); n0 = fmaf(x1.w, x1.w, n0);
      n1 = fmaf(y0.x, y0.x, n1); n1 = fmaf(y0.y, y0.y, n1);
      n1 = fmaf(y0.z, y0.z, n1); n1 = fmaf(y0.w, y0.w, n1);
      n1 = fmaf(y1.x, y1.x, n1); n1 = fmaf(y1.y, y1.y, n1);
      n1 = fmaf(y1.z, y1.z, n1); n1 = fmaf(y1.w, y1.w, n1);
      if (c + 1 < 16) {
        const _Float16* bp = bb + (c + 1) * 2048;
#pragma unroll
        for (int u = 0; u < 4; ++u)
          Bb[(c + 1) & 1][u] = *(const half8*)&bp[u * 512];
      }
      if (w4 < 3) {   /* next-window A into just-freed regs; used in 4 subs */
        F[2 * s]     = a0[(w4 + 1) * 32 + 2 * s];
        F[2 * s + 1] = a0[(w4 + 1) * 32 + 2 * s + 1];
        F[8 + 2 * s] = a1[(w4 + 1) * 32 + 2 * s];
        F[9 + 2 * s] = a1[(w4 + 1) * 32 + 2 * s + 1];
      }
#pragma unroll
      for (int u = 0; u < 4; ++u) {
        acc[0][u] = __builtin_amdgcn_mfma_f32_16x16x32_f16(h0, Bb[c & 1][u], acc[0][u], 0, 0, 0);
        acc[1][u] = __builtin_amdgcn_mfma_f32_16x16x32_f16(h1, Bb[c & 1][u], acc[1][u], 0, 0, 0);
      }
    }
  }

  /* query norms: quads hold disjoint k-regions of the same rows; reduce */
  n0 += __shfl_xor(n0, 16); n0 += __shfl_xor(n0, 32);
  n1 += __shfl_xor(n1, 16); n1 += __shfl_xor(n1, 32);
  if (quad == 0) {
    nqA[mw][qh * 32 + col] = n0;
    nqA[mw][qh * 32 + 16 + col] = n1;
  }

  /* transpose dots: C-layout -> [mod*64+q][p] rows in arena */
#pragma unroll
  for (int t = 0; t < 2; ++t)
#pragma unroll
    for (int u = 0; u < 4; ++u)
#pragma unroll
      for (int j = 0; j < 4; ++j) {
        const int qg = qh * 32 + t * 16 + quad * 4 + j;
        arena[(mw * QB + qg) * EXS + u * 16 + col] = acc[t][u][j];
      }
  __syncthreads();

  /* ---- R3 epilogue: wave = (mwE, phE), lane = query ---- */
  const int mwE = mw, phE = qh;
  float acc2[32];
#pragma unroll
  for (int j = 0; j < 8; ++j) {
    float4 v = *(const float4*)&arena[(mwE * QB + lane) * EXS + phE * 32 + j * 4];
    acc2[4 * j] = v.x; acc2[4 * j + 1] = v.y; acc2[4 * j + 2] = v.z; acc2[4 * j + 3] = v.w;
  }
  const float nq = nqA[mwE][lane];
  const float* np = ws + WS_NP + mwE * CC + phE * 32;
  float mloc = 3.4e38f;
#pragma unroll
  for (int c = 0; c < 32; ++c) {
    float d = sqrtf(fmaxf(nq + np[c] - 2.f * acc2[c], 0.f));
    acc2[c] = d;
    mloc = fminf(mloc, d);
  }
  xmin[w][lane] = mloc;
  __syncthreads();
  const float msh = fminf(fminf(xmin[0][lane], xmin[1][lane]),
                          fminf(xmin[2][lane], xmin[3][lane]));

  float S = 0.f, T = 0.f, M = 0.f;
#pragma unroll
  for (int c = 0; c < 32; ++c) {
    float x = msh - acc2[c];
    float e = __expf(x);
    acc2[c] = e;
    S += e; T = fmaf(e, x, T); M = fmaxf(M, e);
  }
  {
    const int r = (mwE * QB + lane) * EXS + phE * 32;
#pragma unroll
    for (int j = 0; j < 8; ++j)
      *(float4*)&arena[r + 4 * j] = make_float4(acc2[4 * j], acc2[4 * j + 1],
                                                acc2[4 * j + 2], acc2[4 * j + 3]);
  }
  xS[w][lane] = S; xT[w][lane] = T; xM[w][lane] = M;
  __syncthreads();                  /* B1 */

  const float Sr = xS[0][lane] + xS[1][lane];
  const float Sf = xS[2][lane] + xS[3][lane];
  const float Tr = xT[0][lane] + xT[1][lane];
  const float Tf = xT[2][lane] + xT[3][lane];
  const float Mr = fmaxf(xM[0][lane], xM[1][lane]);
  const float Mf = fmaxf(xM[2][lane], xM[3][lane]);
  const float invSr = 1.f / Sr, invSf = 1.f / Sf;
  const float cr = Mr * invSr, cf = Mf * invSf;
  const float hr = __logf(Sr) - Tr * invSr;
  const float hf = __logf(Sf) - Tf * invSf;
  const float wr = cr / (cr + cf), wf = cf / (cr + cf);
  const float dinv = 1.f / (wr * Sr + wf * Sf);

  float po[32];
  {
    const int rOpp = ((1 - mwE) * QB + lane) * EXS + phE * 32;
    const float invOwn = mwE ? invSf : invSr;
    const float invOpp = mwE ? invSr : invSf;
    float kl = 0.f;
#pragma unroll
    for (int j = 0; j < 8; ++j) {
      float4 ev = *(const float4*)&arena[rOpp + 4 * j];
#pragma unroll
      for (int u = 0; u < 4; ++u) {
        const int c = 4 * j + u;
        float pOwn = acc2[c] * invOwn;
        float pOpp = (&ev.x)[u] * invOpp;
        kl = fmaf(pOwn, __logf(pOwn) - pOpp, kl);
        if (mwE == 0)
          po[c] = (wr * acc2[c] + wf * (&ev.x)[u]) * dinv;
      }
    }
    xmin[w][lane] = kl;
    if (w == 0) xI[0][lane] = invSr;
    if (w == 2) xI[1][lane] = invSf;
  }
  __syncthreads();                  /* B2 */

  if (w == 0) {
    const float klrf = xmin[0][lane] + xmin[1][lane];
    ws[WS_GR + q0 + lane] = cr * klrf * (1.f / 64.f);
    const float maskv = (hr > hf && cr > cf) ? 1.f : 0.f;
    float scf = cf, scr = cr, scnt = maskv;
#pragma unroll
    for (int off = 32; off > 0; off >>= 1) {
      scf += __shfl_xor(scf, off);
      scr += __shfl_xor(scr, off);
      scnt += __shfl_xor(scnt, off);
    }
    if (lane == 0) {
      atomicAdd(&ws[WS_SCF], scf);
      atomicAdd(&ws[WS_SCR], scr);
      atomicAdd(&ws[WS_CNT], scnt);
    }
  } else if (w == 2) {
    const float klfr = xmin[2][lane] + xmin[3][lane];
    ws[WS_GF + q0 + lane] = cf * klfr * (1.f / 64.f);
  }

  float* out_pf = out + 2;
  float* out_pr = out + 2 + (size_t)QTOT * CC;
  float* out_po = out + 2 + (size_t)2 * QTOT * CC;
#pragma unroll
  for (int i = 0; i < 4; ++i) {
    const int g = tid + 256 * i, row = g >> 4, c4 = g & 15;
    const float sR = xI[0][row], sF = xI[1][row];
    float4 vr = *(const float4*)&arena[row * EXS + c4 * 4];
    float4 vf = *(const float4*)&arena[(QB + row) * EXS + c4 * 4];
    vr.x *= sR; vr.y *= sR; vr.z *= sR; vr.w *= sR;
    vf.x *= sF; vf.y *= sF; vf.z *= sF; vf.w *= sF;
    *(float4*)(out_pr + (size_t)(q0 + row) * CC + c4 * 4) = vr;
    *(float4*)(out_pf + (size_t)(q0 + row) * CC + c4 * 4) = vf;
  }
  __syncthreads();                  /* B3 */

  if (mwE == 0) {
    const int r = lane * EXS + phE * 32;
#pragma unroll
    for (int j = 0; j < 8; ++j)
      *(float4*)&arena[r + 4 * j] = make_float4(po[4 * j], po[4 * j + 1],
                                                po[4 * j + 2], po[4 * j + 3]);
  }
  __syncthreads();                  /* B4 */
#pragma unroll
  for (int i = 0; i < 4; ++i) {
    const int g = tid + 256 * i, row = g >> 4, c4 = g & 15;
    float4 v = *(const float4*)&arena[row * EXS + c4 * 4];
    *(float4*)(out_po + (size_t)(q0 + row) * CC + c4 * 4) = v;
  }
}

/* K2: masked sums over g arrays using the global n_r from K1. */
__global__ __launch_bounds__(256) void k2_reduce(float* ws) {
  const int nr = (int)ws[WS_CNT];
  const int nf = QTOT - nr;
  float sf = 0.f, sr = 0.f;
  for (int i = blockIdx.x * 256 + threadIdx.x; i < QTOT; i += gridDim.x * 256) {
    if (i < nf) sf += ws[WS_GF + i];
    if (i < nr) sr += ws[WS_GR + i];
  }
#pragma unroll
  for (int off = 32; off > 0; off >>= 1) {
    sf += __shfl_xor(sf, off);
    sr += __shfl_xor(sr, off);
  }
  if ((threadIdx.x & 63) == 0) {
    atomicAdd(&ws[WS_MGF], sf);
    atomicAdd(&ws[WS_MGR], sr);
  }
}

__global__ void k3_final(const float* ws, float* out) {
  if (threadIdx.x == 0) {
    out[0] = ws[WS_MGF] / ws[WS_SCF];
    out[1] = ws[WS_MGR] / ws[WS_SCR];
  }
}

extern "C" void kernel_launch(void* const* d_in, const int* in_sizes, int n_in,
                              void* d_out, int out_size, void* d_ws, size_t ws_size,
                              hipStream_t stream) {
  const float* ctx_r = (const float*)d_in[0];
  const float* ctx_f = (const float*)d_in[1];
  const float* tgt_r = (const float*)d_in[2];
  const float* tgt_f = (const float*)d_in[3];
  float* out = (float*)d_out;
  float* ws = (float*)d_ws;

  k0_prep<<<128, 64, 0, stream>>>(ctx_r, ctx_f, ws);
  k1_main<<<QTOT / QB, BLK, 0, stream>>>(tgt_r, tgt_f, ws, out);
  k2_reduce<<<64, 256, 0, stream>>>(ws);
  k3_final<<<1, 64, 0, stream>>>(ws, out);
}

// Round 3
// 348.683 us; speedup vs baseline: 1.0324x; 1.0324x over previous
//
#include <hip/hip_runtime.h>
#include <math.h>

#define QTOT 65536
#define CC 64
#define DD 512
#define QB 64            /* queries per block */
#define BLK 256
#define EXS 68           /* dots/e-value row stride in floats (272 B) */

typedef _Float16 half8 __attribute__((ext_vector_type(8)));
typedef float floatx4 __attribute__((ext_vector_type(4)));

/* ws float layout:
   [0] sum c_f  [1] sum c_r  [2] n_r  [3] masked g_f  [4] masked g_r
   [16..144) proto norms (rgb 64 then flow 64)
   [256..256+65536) g_f   [256+65536..) g_r
   [256+2*65536 ..) f16 protos, window-relabeled frag order (see k0), 32768 halfs/mod */
enum { WS_SCF = 0, WS_SCR = 1, WS_CNT = 2, WS_MGF = 3, WS_MGR = 4,
       WS_NP = 16, WS_GF = 256, WS_GR = 256 + QTOT, WS_PH = 256 + 2 * QTOT };

/* K0: proto norms (fp32) + f16 conversion into the window-relabeled frag order.
   k-group g (orig k = 8g..8g+7) -> chunk c = (g>>4)*4 + (g&3), kk = ((g>>2)&3)*8.
   Pairs with k1's A-side: lane-quad owns the contiguous 128-B region
   (orig-k [quad*32, quad*32+32)) of each 512-B window. */
__global__ __launch_bounds__(64) void k0_prep(
    const float* __restrict__ ctx_r, const float* __restrict__ ctx_f,
    float* ws) {
  const int b = blockIdx.x;        /* 0..127 = mod*64 + proto */
  const int lane = threadIdx.x;
  const int m = b >> 6, p = b & 63;
  const float* row = ((m == 0) ? ctx_r : ctx_f) + (size_t)p * DD;
  const float4* r4 = (const float4*)row;
  float s = 0.f;
#pragma unroll
  for (int i = 0; i < 2; ++i) {
    float4 v = r4[lane + i * 64];
    s = fmaf(v.x, v.x, s); s = fmaf(v.y, v.y, s);
    s = fmaf(v.z, v.z, s); s = fmaf(v.w, v.w, s);
  }
#pragma unroll
  for (int off = 32; off > 0; off >>= 1) s += __shfl_xor(s, off);
  if (lane == 0) ws[WS_NP + b] = s;
  if (b == 0 && lane < 16) ws[lane] = 0.f;

  /* f16 conversion: lane = k-group g; dest chunk/kk per window relabeling */
  _Float16* hF = (_Float16*)(ws + WS_PH);
  float4 a = r4[lane * 2], c = r4[lane * 2 + 1];
  half8 h;
  h[0] = (_Float16)a.x; h[1] = (_Float16)a.y; h[2] = (_Float16)a.z; h[3] = (_Float16)a.w;
  h[4] = (_Float16)c.x; h[5] = (_Float16)c.y; h[6] = (_Float16)c.z; h[7] = (_Float16)c.w;
  const int chunk = (lane >> 4) * 4 + (lane & 3);
  const int kk = ((lane >> 2) & 3) * 8;
  *(half8*)&hF[m * 32768 + chunk * 2048 + p * 32 + kk] = h;
}

/* K1: wave w = mw*2+qh (modality, query-half). MFMA 16x16x32 f16.
   A is read in contiguous 128-B-per-row regions (round-2 layout), now with a
   DOUBLE-BUFFERED window pipeline: F[2][16], buffer parity = window parity.
   Slot (p, j) is consumed at window w4 (parity p) sub j/2 and immediately
   reloaded with window w4+2's data -> prefetch distance = 8 sub-chunks
   (~800-1500 cyc) >= ~900-cyc HBM latency, vs the previous 4-sub distance
   that stalled every window. B deepened to distance-2 (reload Bb[c&1] with
   chunk c+2 after its MFMAs; covers ~200-300-cyc L2 latency).
   No LDS / no barriers in the loop. Epilogue (verified) byte-identical. */
__global__ __launch_bounds__(BLK, 2) void k1_main(
    const float* __restrict__ tgt_r, const float* __restrict__ tgt_f,
    float* ws, float* __restrict__ out) {
  __shared__ __align__(16) float arena[2 * QB * EXS];  /* 34816 B */
  __shared__ float xmin[4][QB];
  __shared__ float xS[4][QB];
  __shared__ float xT[4][QB];
  __shared__ float xM[4][QB];
  __shared__ float xI[2][QB];
  __shared__ float nqA[2][QB];

  const int tid = threadIdx.x;
  const int w = tid >> 6, lane = tid & 63;
  const int mw = w >> 1, qh = w & 1;
  const int col = lane & 15, quad = lane >> 4;
  const int q0 = blockIdx.x * QB;

  const _Float16* hF = (const _Float16*)(ws + WS_PH);
  const float* tgt = mw ? tgt_f : tgt_r;
  /* lane's region base: row (qh*32 [+16] + col), byte offset quad*128 */
  const float4* a0 = (const float4*)(tgt + (size_t)(q0 + qh * 32 + col) * DD) + quad * 8;
  const float4* a1 = (const float4*)(tgt + (size_t)(q0 + qh * 32 + 16 + col) * DD) + quad * 8;
  const _Float16* bb = hF + mw * 32768 + col * 32 + quad * 8;

  floatx4 acc[2][4];
#pragma unroll
  for (int t = 0; t < 2; ++t)
#pragma unroll
    for (int u = 0; u < 4; ++u) acc[t][u] = (floatx4){0.f, 0.f, 0.f, 0.f};

  /* F[p][j]: j=0..7 t0-row granules, j=8..15 t1-row granules of window w4
     with w4&1==p.  Bb[c&1][u]: B fragments of chunk c. */
  float4 F[2][16];
  half8 Bb[2][4];
#pragma unroll
  for (int j = 0; j < 8; ++j) { F[0][j] = a0[j]; F[0][8 + j] = a1[j]; }
#pragma unroll
  for (int u = 0; u < 4; ++u) Bb[0][u] = *(const half8*)&bb[u * 512];
#pragma unroll
  for (int j = 0; j < 8; ++j) { F[1][j] = a0[32 + j]; F[1][8 + j] = a1[32 + j]; }
#pragma unroll
  for (int u = 0; u < 4; ++u) Bb[1][u] = *(const half8*)&bb[2048 + u * 512];

  float n0 = 0.f, n1 = 0.f;
#pragma unroll
  for (int w4 = 0; w4 < 4; ++w4) {
    const int p = w4 & 1;
#pragma unroll
    for (int s = 0; s < 4; ++s) {
      const int c = w4 * 4 + s;
      float4 x0 = F[p][2 * s], x1 = F[p][2 * s + 1];
      float4 y0 = F[p][8 + 2 * s], y1 = F[p][9 + 2 * s];
      half8 h0, h1;
      h0[0] = (_Float16)x0.x; h0[1] = (_Float16)x0.y; h0[2] = (_Float16)x0.z; h0[3] = (_Float16)x0.w;
      h0[4] = (_Float16)x1.x; h0[5] = (_Float16)x1.y; h0[6] = (_Float16)x1.z; h0[7] = (_Float16)x1.w;
      h1[0] = (_Float16)y0.x; h1[1] = (_Float16)y0.y; h1[2] = (_Float16)y0.z; h1[3] = (_Float16)y0.w;
      h1[4] = (_Float16)y1.x; h1[5] = (_Float16)y1.y; h1[6] = (_Float16)y1.z; h1[7] = (_Float16)y1.w;
      /* slots consumed -> reload with window w4+2 (same parity), distance 8 subs */
      if (w4 < 2) {
        F[p][2 * s]     = a0[(w4 + 2) * 32 + 2 * s];
        F[p][2 * s + 1] = a0[(w4 + 2) * 32 + 2 * s + 1];
        F[p][8 + 2 * s] = a1[(w4 + 2) * 32 + 2 * s];
        F[p][9 + 2 * s] = a1[(w4 + 2) * 32 + 2 * s + 1];
      }
      n0 = fmaf(x0.x, x0.x, n0); n0 = fmaf(x0.y, x0.y, n0);
      n0 = fmaf(x0.z, x0.z, n0); n0 = fmaf(x0.w, x0.w, n0);
      n0 = fmaf(x1.x, x1.x, n0); n0 = fmaf(x1.y, x1.y, n0);
      n0 = fmaf(x1.z, x1.z, n0); n0 = fmaf(x1.w, x1.w, n0);
      n1 = fmaf(y0.x, y0.x, n1); n1 = fmaf(y0.y, y0.y, n1);
      n1 = fmaf(y0.z, y0.z, n1); n1 = fmaf(y0.w, y0.w, n1);
      n1 = fmaf(y1.x, y1.x, n1); n1 = fmaf(y1.y, y1.y, n1);
      n1 = fmaf(y1.z, y1.z, n1); n1 = fmaf(y1.w, y1.w, n1);
#pragma unroll
      for (int u = 0; u < 4; ++u) {
        acc[0][u] = __builtin_amdgcn_mfma_f32_16x16x32_f16(h0, Bb[c & 1][u], acc[0][u], 0, 0, 0);
        acc[1][u] = __builtin_amdgcn_mfma_f32_16x16x32_f16(h1, Bb[c & 1][u], acc[1][u], 0, 0, 0);
      }
      /* B chunk c done -> reload its buffer with chunk c+2, distance 2 subs */
      if (c + 2 < 16) {
        const _Float16* bp = bb + (c + 2) * 2048;
#pragma unroll
        for (int u = 0; u < 4; ++u)
          Bb[c & 1][u] = *(const half8*)&bp[u * 512];
      }
    }
  }

  /* query norms: quads hold disjoint k-regions of the same rows; reduce */
  n0 += __shfl_xor(n0, 16); n0 += __shfl_xor(n0, 32);
  n1 += __shfl_xor(n1, 16); n1 += __shfl_xor(n1, 32);
  if (quad == 0) {
    nqA[mw][qh * 32 + col] = n0;
    nqA[mw][qh * 32 + 16 + col] = n1;
  }

  /* transpose dots: C-layout -> [mod*64+q][p] rows in arena */
#pragma unroll
  for (int t = 0; t < 2; ++t)
#pragma unroll
    for (int u = 0; u < 4; ++u)
#pragma unroll
      for (int j = 0; j < 4; ++j) {
        const int qg = qh * 32 + t * 16 + quad * 4 + j;
        arena[(mw * QB + qg) * EXS + u * 16 + col] = acc[t][u][j];
      }
  __syncthreads();

  /* ---- R3 epilogue: wave = (mwE, phE), lane = query ---- */
  const int mwE = mw, phE = qh;
  float acc2[32];
#pragma unroll
  for (int j = 0; j < 8; ++j) {
    float4 v = *(const float4*)&arena[(mwE * QB + lane) * EXS + phE * 32 + j * 4];
    acc2[4 * j] = v.x; acc2[4 * j + 1] = v.y; acc2[4 * j + 2] = v.z; acc2[4 * j + 3] = v.w;
  }
  const float nq = nqA[mwE][lane];
  const float* np = ws + WS_NP + mwE * CC + phE * 32;
  float mloc = 3.4e38f;
#pragma unroll
  for (int c = 0; c < 32; ++c) {
    float d = sqrtf(fmaxf(nq + np[c] - 2.f * acc2[c], 0.f));
    acc2[c] = d;
    mloc = fminf(mloc, d);
  }
  xmin[w][lane] = mloc;
  __syncthreads();
  const float msh = fminf(fminf(xmin[0][lane], xmin[1][lane]),
                          fminf(xmin[2][lane], xmin[3][lane]));

  float S = 0.f, T = 0.f, M = 0.f;
#pragma unroll
  for (int c = 0; c < 32; ++c) {
    float x = msh - acc2[c];
    float e = __expf(x);
    acc2[c] = e;
    S += e; T = fmaf(e, x, T); M = fmaxf(M, e);
  }
  {
    const int r = (mwE * QB + lane) * EXS + phE * 32;
#pragma unroll
    for (int j = 0; j < 8; ++j)
      *(float4*)&arena[r + 4 * j] = make_float4(acc2[4 * j], acc2[4 * j + 1],
                                                acc2[4 * j + 2], acc2[4 * j + 3]);
  }
  xS[w][lane] = S; xT[w][lane] = T; xM[w][lane] = M;
  __syncthreads();                  /* B1 */

  const float Sr = xS[0][lane] + xS[1][lane];
  const float Sf = xS[2][lane] + xS[3][lane];
  const float Tr = xT[0][lane] + xT[1][lane];
  const float Tf = xT[2][lane] + xT[3][lane];
  const float Mr = fmaxf(xM[0][lane], xM[1][lane]);
  const float Mf = fmaxf(xM[2][lane], xM[3][lane]);
  const float invSr = 1.f / Sr, invSf = 1.f / Sf;
  const float cr = Mr * invSr, cf = Mf * invSf;
  const float hr = __logf(Sr) - Tr * invSr;
  const float hf = __logf(Sf) - Tf * invSf;
  const float wr = cr / (cr + cf), wf = cf / (cr + cf);
  const float dinv = 1.f / (wr * Sr + wf * Sf);

  float po[32];
  {
    const int rOpp = ((1 - mwE) * QB + lane) * EXS + phE * 32;
    const float invOwn = mwE ? invSf : invSr;
    const float invOpp = mwE ? invSr : invSf;
    float kl = 0.f;
#pragma unroll
    for (int j = 0; j < 8; ++j) {
      float4 ev = *(const float4*)&arena[rOpp + 4 * j];
#pragma unroll
      for (int u = 0; u < 4; ++u) {
        const int c = 4 * j + u;
        float pOwn = acc2[c] * invOwn;
        float pOpp = (&ev.x)[u] * invOpp;
        kl = fmaf(pOwn, __logf(pOwn) - pOpp, kl);
        if (mwE == 0)
          po[c] = (wr * acc2[c] + wf * (&ev.x)[u]) * dinv;
      }
    }
    xmin[w][lane] = kl;
    if (w == 0) xI[0][lane] = invSr;
    if (w == 2) xI[1][lane] = invSf;
  }
  __syncthreads();                  /* B2 */

  if (w == 0) {
    const float klrf = xmin[0][lane] + xmin[1][lane];
    ws[WS_GR + q0 + lane] = cr * klrf * (1.f / 64.f);
    const float maskv = (hr > hf && cr > cf) ? 1.f : 0.f;
    float scf = cf, scr = cr, scnt = maskv;
#pragma unroll
    for (int off = 32; off > 0; off >>= 1) {
      scf += __shfl_xor(scf, off);
      scr += __shfl_xor(scr, off);
      scnt += __shfl_xor(scnt, off);
    }
    if (lane == 0) {
      atomicAdd(&ws[WS_SCF], scf);
      atomicAdd(&ws[WS_SCR], scr);
      atomicAdd(&ws[WS_CNT], scnt);
    }
  } else if (w == 2) {
    const float klfr = xmin[2][lane] + xmin[3][lane];
    ws[WS_GF + q0 + lane] = cf * klfr * (1.f / 64.f);
  }

  float* out_pf = out + 2;
  float* out_pr = out + 2 + (size_t)QTOT * CC;
  float* out_po = out + 2 + (size_t)2 * QTOT * CC;
#pragma unroll
  for (int i = 0; i < 4; ++i) {
    const int g = tid + 256 * i, row = g >> 4, c4 = g & 15;
    const float sR = xI[0][row], sF = xI[1][row];
    float4 vr = *(const float4*)&arena[row * EXS + c4 * 4];
    float4 vf = *(const float4*)&arena[(QB + row) * EXS + c4 * 4];
    vr.x *= sR; vr.y *= sR; vr.z *= sR; vr.w *= sR;
    vf.x *= sF; vf.y *= sF; vf.z *= sF; vf.w *= sF;
    *(float4*)(out_pr + (size_t)(q0 + row) * CC + c4 * 4) = vr;
    *(float4*)(out_pf + (size_t)(q0 + row) * CC + c4 * 4) = vf;
  }
  __syncthreads();                  /* B3 */

  if (mwE == 0) {
    const int r = lane * EXS + phE * 32;
#pragma unroll
    for (int j = 0; j < 8; ++j)
      *(float4*)&arena[r + 4 * j] = make_float4(po[4 * j], po[4 * j + 1],
                                                po[4 * j + 2], po[4 * j + 3]);
  }
  __syncthreads();                  /* B4 */
#pragma unroll
  for (int i = 0; i < 4; ++i) {
    const int g = tid + 256 * i, row = g >> 4, c4 = g & 15;
    float4 v = *(const float4*)&arena[row * EXS + c4 * 4];
    *(float4*)(out_po + (size_t)(q0 + row) * CC + c4 * 4) = v;
  }
}

/* K2: masked sums over g arrays using the global n_r from K1. */
__global__ __launch_bounds__(256) void k2_reduce(float* ws) {
  const int nr = (int)ws[WS_CNT];
  const int nf = QTOT - nr;
  float sf = 0.f, sr = 0.f;
  for (int i = blockIdx.x * 256 + threadIdx.x; i < QTOT; i += gridDim.x * 256) {
    if (i < nf) sf += ws[WS_GF + i];
    if (i < nr) sr += ws[WS_GR + i];
  }
#pragma unroll
  for (int off = 32; off > 0; off >>= 1) {
    sf += __shfl_xor(sf, off);
    sr += __shfl_xor(sr, off);
  }
  if ((threadIdx.x & 63) == 0) {
    atomicAdd(&ws[WS_MGF], sf);
    atomicAdd(&ws[WS_MGR], sr);
  }
}

__global__ void k3_final(const float* ws, float* out) {
  if (threadIdx.x == 0) {
    out[0] = ws[WS_MGF] / ws[WS_SCF];
    out[1] = ws[WS_MGR] / ws[WS_SCR];
  }
}

extern "C" void kernel_launch(void* const* d_in, const int* in_sizes, int n_in,
                              void* d_out, int out_size, void* d_ws, size_t ws_size,
                              hipStream_t stream) {
  const float* ctx_r = (const float*)d_in[0];
  const float* ctx_f = (const float*)d_in[1];
  const float* tgt_r = (const float*)d_in[2];
  const float* tgt_f = (const float*)d_in[3];
  float* out = (float*)d_out;
  float* ws = (float*)d_ws;

  k0_prep<<<128, 64, 0, stream>>>(ctx_r, ctx_f, ws);
  k1_main<<<QTOT / QB, BLK, 0, stream>>>(tgt_r, tgt_f, ws, out);
  k2_reduce<<<64, 256, 0, stream>>>(ws);
  k3_final<<<1, 64, 0, stream>>>(ws, out);
}